// Round 1
// 476.624 us; speedup vs baseline: 1.0499x; 1.0499x over previous
//
#include <hip/hip_runtime.h>
#include <hip/hip_bf16.h>
#include <math.h>
#include <stdint.h>

// ---- problem constants ----
#define S_LEN 4680
#define DIMSZ 1536
#define NH    12
#define HD    128
#define FRAME 1560
#define NGRP  74        // padded 64-key/-q groups (74*64 = 4736)
#define PANH  (NGRP * 8192)   // f16 elems per head in a panelized tensor
#define NSLOT 150       // (q-tile, chunk) slots per head: 12*2 + 12*4 + 13*6

typedef _Float16 f16;
typedef _Float16 f16x8 __attribute__((ext_vector_type(8)));
typedef _Float16 f16x4 __attribute__((ext_vector_type(4)));
typedef _Float16 f16x2 __attribute__((ext_vector_type(2)));
typedef __fp16   fp16x2 __attribute__((ext_vector_type(2)));
typedef float    f32x4  __attribute__((ext_vector_type(4)));
typedef float    f32x16 __attribute__((ext_vector_type(16)));
typedef int      v2i    __attribute__((ext_vector_type(2)));

__device__ __forceinline__ void async16(const void* g, void* l) {
    __builtin_amdgcn_global_load_lds((const __attribute__((address_space(1))) void*)g,
                                     (__attribute__((address_space(3))) void*)l, 16, 0, 0);
}

union PkCast { fp16x2 v; int i; };
union FragCast { int w[4]; f16x8 v; };

// ============================================================
// all f32->f16 casts in one dispatch: y=0 x, y=1..4 weights
// ============================================================
__global__ __launch_bounds__(256) void cast_all(const float* __restrict__ x,
                                                const float* __restrict__ wq,
                                                const float* __restrict__ wk,
                                                const float* __restrict__ wv,
                                                const float* __restrict__ wo,
                                                f16* __restrict__ xh,
                                                f16* __restrict__ wh) {
    int y = blockIdx.y;
    int i = blockIdx.x * 256 + threadIdx.x;
    if (y == 0) {
        if (i < (S_LEN * DIMSZ) / 4) {
            float4 v = ((const float4*)x)[i];
            f16x4 h; h[0]=(f16)v.x; h[1]=(f16)v.y; h[2]=(f16)v.z; h[3]=(f16)v.w;
            ((f16x4*)xh)[i] = h;
        }
    } else {
        const int nW4 = (DIMSZ * DIMSZ) / 4;
        if (i < nW4) {
            const float* src = (y==1)?wq:(y==2)?wk:(y==3)?wv:wo;
            float4 v = ((const float4*)src)[i];
            f16x4 h; h[0]=(f16)v.x; h[1]=(f16)v.y; h[2]=(f16)v.z; h[3]=(f16)v.w;
            ((f16x4*)wh)[(size_t)(y-1)*nW4 + i] = h;
        }
    }
}

// ============================================================
// Fused QKV GEMM (m97 structure), grid (37,12,3).
// z=0/1: pre-norm Q/K, f16 row-major. z=2: V, f16 panelized Vt.
// Vt panels: [head][key-group][8 kchunks][128 d][8 keys]
// ============================================================
__global__ __launch_bounds__(256) void gemm_qkv(const f16* __restrict__ A,
                                                const f16* __restrict__ Bq,
                                                const f16* __restrict__ Bk,
                                                const f16* __restrict__ Bv,
                                                const float* __restrict__ bq,
                                                const float* __restrict__ bk,
                                                const float* __restrict__ bv,
                                                f16* __restrict__ preq,
                                                f16* __restrict__ prek,
                                                f16* __restrict__ vtp) {
    int z = blockIdx.z;
    const f16* B = (z==0) ? Bq : (z==1) ? Bk : Bv;
    const float* bias = (z==0) ? bq : (z==1) ? bk : bv;

    __shared__ __align__(16) f16 Al[128 * 64];
    __shared__ __align__(16) f16 Bl[128 * 64];
    int tid = threadIdx.x;
    int lane = tid & 63, wv = tid >> 6;
    int l16 = lane & 15, quad = lane >> 4;
    int wr = (wv >> 1) * 64, wc = (wv & 1) * 64;
    int m0 = blockIdx.x * 128, n0 = blockIdx.y * 128;

    f32x4 acc[4][4] = {};

    for (int kb = 0; kb < DIMSZ; kb += 64) {
        __syncthreads();
#pragma unroll
        for (int j = 0; j < 4; j++) {
            int s = j * 256 + wv * 64 + lane;
            int r = s >> 3, cc = s & 7;
            const f16* src = A + (size_t)min(m0 + r, S_LEN - 1) * DIMSZ + kb + ((cc ^ (r & 7)) << 3);
            async16(src, (char*)Al + (j * 4096 + wv * 1024));
        }
#pragma unroll
        for (int j = 0; j < 4; j++) {
            int s = j * 256 + wv * 64 + lane;
            int r = s >> 3, cc = s & 7;
            const f16* src = B + (size_t)(n0 + r) * DIMSZ + kb + ((cc ^ (r & 7)) << 3);
            async16(src, (char*)Bl + (j * 4096 + wv * 1024));
        }
        __builtin_amdgcn_s_waitcnt(0x0f70);
        __syncthreads();

#pragma unroll
        for (int kc = 0; kc < 2; kc++) {
            f16x8 af[4], bf[4];
#pragma unroll
            for (int i = 0; i < 4; i++) {
                int ar = wr + i * 16 + l16;
                af[i] = *(const f16x8*)((const char*)Al + ar * 128 + (((kc * 4 + quad) ^ (ar & 7)) << 4));
                int br = wc + i * 16 + l16;
                bf[i] = *(const f16x8*)((const char*)Bl + br * 128 + (((kc * 4 + quad) ^ (br & 7)) << 4));
            }
#pragma unroll
            for (int mi = 0; mi < 4; mi++)
#pragma unroll
                for (int ni = 0; ni < 4; ni++)
                    acc[mi][ni] = __builtin_amdgcn_mfma_f32_16x16x32_f16(af[mi], bf[ni], acc[mi][ni], 0, 0, 0);
        }
    }

    if (z < 2) {
        f16* C = (z == 0) ? preq : prek;
#pragma unroll
        for (int mi = 0; mi < 4; mi++)
#pragma unroll
            for (int ni = 0; ni < 4; ni++) {
                int col = n0 + wc + ni * 16 + l16;
                float bv_ = bias[col];
#pragma unroll
                for (int r = 0; r < 4; r++) {
                    int row = m0 + wr + mi * 16 + quad * 4 + r;
                    if (row < S_LEN) C[(size_t)row * DIMSZ + col] = (f16)(acc[mi][ni][r] + bv_);
                }
            }
    } else {
#pragma unroll
        for (int mi = 0; mi < 4; mi++)
#pragma unroll
            for (int ni = 0; ni < 4; ni++) {
                int col  = n0 + wc + ni * 16 + l16;
                int vhead = col >> 7, d = col & 127;
                int base = m0 + wr + mi * 16 + quad * 4;   // 4 consecutive keys
                if (base < S_LEN) {
                    float bv_ = bias[col];
                    f16x4 h;
#pragma unroll
                    for (int r = 0; r < 4; r++) h[r] = (f16)(acc[mi][ni][r] + bv_);
                    size_t off = (size_t)vhead * PANH + (size_t)(base >> 6) * 8192
                               + ((base >> 3) & 7) * 1024 + d * 8 + (base & 7);
                    *(f16x4*)(vtp + off) = h;
                }
            }
    }
}

// ============================================================
// RMSNorm + RoPE -> panelized Q/K: [head][q-group][16 dchunks][64 q][8 d]
// grid (S_LEN, 2): y=0 Q, y=1 K
// ============================================================
__global__ __launch_bounds__(256) void norm_rope(const f16* __restrict__ preq,
                                                 const f16* __restrict__ prek,
                                                 const float* __restrict__ gq,
                                                 const float* __restrict__ gk,
                                                 const float* __restrict__ freqs,
                                                 f16* __restrict__ Qp,
                                                 f16* __restrict__ Kp) {
    int s = blockIdx.x, which = blockIdx.y;
    int t = threadIdx.x;
    const f16* pre = which ? prek : preq;
    const float* g = which ? gk : gq;
    f16* dst = which ? Kp : Qp;
    const f16* row = pre + (size_t)s * DIMSZ + t * 6;

    float v[6];
    float ss = 0.f;
#pragma unroll
    for (int i = 0; i < 3; i++) {
        f16x2 hp = *(const f16x2*)(row + 2 * i);
        v[2*i] = (float)hp[0]; v[2*i+1] = (float)hp[1];
        ss += v[2*i]*v[2*i] + v[2*i+1]*v[2*i+1];
    }
#pragma unroll
    for (int off = 32; off; off >>= 1) ss += __shfl_xor(ss, off);
    __shared__ float red[4];
    if ((t & 63) == 0) red[t >> 6] = ss;
    __syncthreads();
    float tot = red[0] + red[1] + red[2] + red[3];
    float rms = rsqrtf(tot * (1.0f / DIMSZ) + 1e-6f);

    int tpos = s / FRAME;
    int rem  = s % FRAME;
    int ypos = rem / 52;
    int xpos = s % 52;

#pragma unroll
    for (int u = 0; u < 3; u++) {
        int c = t * 6 + u * 2;
        int head = c >> 7;
        int d = c & 127;
        int j = d >> 1;
        int idx = (j < 22) ? tpos : ((j < 43) ? ypos : xpos);
        float ang = freqs[idx * 64 + j];
        float sn, cs;
        __sincosf(ang, &sn, &cs);
        float vr = v[u * 2]     * rms * g[c];
        float vi = v[u * 2 + 1] * rms * g[c + 1];
        f16* o = dst + (size_t)head * PANH + (size_t)(s >> 6) * 8192
               + (d >> 3) * 512 + (s & 63) * 8 + (d & 7);
        o[0] = (f16)(vr * cs - vi * sn);
        o[1] = (f16)(vr * sn + vi * cs);
    }
}

// ============================================================
// Attention partials. Block = 2 waves x 64 q (128 q-tile), head, chunk.
// Fine chunking: 2/4/6 chunks per tile by frame count -> grid (150, 12).
// 32x32x16 MFMA, S^T = K Q^T, O^T = V^T P^T.
// LDS = byte-image of panelized global groups -> conflict-free reads.
// NEW: double-buffered LDS (2x32KB) + counted vmcnt(16) prefetch pipeline
// (T3/T4 pattern): next group's 16 global_load_lds stay in flight across
// the raw s_barrier while the current group computes. Replaces the
// per-group vmcnt(0)+__syncthreads drain that made the kernel latency-
// bound (MfmaUtil 20% at 18% occupancy).
// ============================================================
__global__ __launch_bounds__(128, 2) void attn_part(const f16* __restrict__ Qp,
                                                    const f16* __restrict__ Kp,
                                                    const f16* __restrict__ Vp,
                                                    f16* __restrict__ Opart,
                                                    float* __restrict__ lpart) {
    int bx = blockIdx.x, head = blockIdx.y;
    int t, c, NC2;
    if (bx < 24)      { t = bx >> 1;             c = bx & 1;       NC2 = 2; }
    else if (bx < 72) { t = 12 + ((bx - 24) >> 2); c = (bx - 24) & 3; NC2 = 4; }
    else              { t = 24 + (bx - 72) / 6;  c = (bx - 72) % 6; NC2 = 6; }

    int qlast = min(t * 128 + 127, S_LEN - 1);
    int nfrm  = qlast / FRAME + 1;
    int kvend = nfrm * FRAME; if (kvend > S_LEN) kvend = S_LEN;
    int nG    = (kvend + 63) >> 6;
    int g0 = (c * nG) / NC2, g1 = ((c + 1) * nG) / NC2;
    int limB = ((t * 128) / FRAME + 1) * FRAME;

    int tid = threadIdx.x, lane = tid & 63, wv = tid >> 6;
    int l31 = lane & 31, lh = lane >> 5;
    int qw = t * 128 + wv * 64;

    __shared__ __align__(16) char smem[65536];

    // Q B-frags from panelized global (coalesced), pre-scaled
    const f16* Qg = Qp + ((size_t)head * NGRP + (qw >> 6)) * 8192;
    f16x8 bqf[2][8];
#pragma unroll
    for (int nt = 0; nt < 2; nt++)
#pragma unroll
        for (int ks = 0; ks < 8; ks++) {
            f16x8 vq = *(const f16x8*)(Qg + (2 * ks + lh) * 512 + (l31 + 32 * nt) * 8);
            bqf[nt][ks] = vq * (f16)0.08838834764831845f;
        }

    int lim[2];
#pragma unroll
    for (int nt = 0; nt < 2; nt++) {
        int q = qw + l31 + 32 * nt;
        lim[nt] = (q / FRAME + 1) * FRAME;
    }

    f32x16 oacc[4][2] = {};
    float lp[2] = {0.f, 0.f};

    int koff = lh * 1024 + l31 * 16;
    int voff = lh * 2048 + l31 * 16;

    const f16* Kh = Kp + (size_t)head * NGRP * 8192;
    const f16* Vh = Vp + (size_t)head * NGRP * 8192;

    // ---- prologue: stage group g0 into buffer 0 (16 async16 per wave) ----
#pragma unroll
    for (int i = 0; i < 8; i++) {
        int s = i * 2 + wv;
        async16(Kh + (size_t)g0 * 8192 + s * 512 + lane * 8,
                (char*)smem + s * 1024 + lane * 16);
        async16(Vh + (size_t)g0 * 8192 + s * 512 + lane * 8,
                (char*)smem + 16384 + s * 1024 + lane * 16);
    }

    int cur = 0;
    for (int g = g0; g < g1; g++) {
        int kb = g * 64;

        // ---- prefetch next group into the other buffer, counted wait ----
        if (g + 1 < g1) {
            int nb = (cur ^ 1) << 15;
#pragma unroll
            for (int i = 0; i < 8; i++) {
                int s = i * 2 + wv;
                async16(Kh + (size_t)(g + 1) * 8192 + s * 512 + lane * 8,
                        (char*)smem + nb + s * 1024 + lane * 16);
                async16(Vh + (size_t)(g + 1) * 8192 + s * 512 + lane * 8,
                        (char*)smem + nb + 16384 + s * 1024 + lane * 16);
            }
            // 32 outstanding: oldest 16 = this group, newest 16 = prefetch.
            // vmcnt retires in-order -> wait this group's only.
            asm volatile("s_waitcnt vmcnt(16)" ::: "memory");
        } else {
            asm volatile("s_waitcnt vmcnt(0)" ::: "memory");
        }
        __builtin_amdgcn_s_barrier();

        const char* smc = (const char*)smem + (cur << 15);
        bool domask = (kb + 64 > limB);

#pragma unroll
        for (int kt = 0; kt < 2; kt++) {
            // ---- S^T = K Q^T ----
            f32x16 sc0 = {}, sc1 = {};
#pragma unroll
            for (int h = 0; h < 2; h++) {
                f16x8 ka[4];
#pragma unroll
                for (int i = 0; i < 4; i++)
                    ka[i] = *(const f16x8*)(smc + koff + (h * 4 + i) * 2048 + kt * 512);
#pragma unroll
                for (int i = 0; i < 4; i++) {
                    sc0 = __builtin_amdgcn_mfma_f32_32x32x16_f16(ka[i], bqf[0][h*4+i], sc0, 0, 0, 0);
                    sc1 = __builtin_amdgcn_mfma_f32_32x32x16_f16(ka[i], bqf[1][h*4+i], sc1, 0, 0, 0);
                }
            }

            // ---- mask + exp + pack ----
            int w[2][8];
            int keyb = kb + kt * 32 + 4 * lh;
#pragma unroll
            for (int nt = 0; nt < 2; nt++) {
#pragma unroll
                for (int p = 0; p < 8; p++) {
                    const int r0 = 2 * p;
                    float s0 = (nt == 0) ? sc0[r0]     : sc1[r0];
                    float s1 = (nt == 0) ? sc0[r0 + 1] : sc1[r0 + 1];
                    if (domask) {
                        int k0 = keyb + (r0 & 3) + 8 * (r0 >> 2);
                        if (k0     >= lim[nt]) s0 = -1e30f;
                        if (k0 + 1 >= lim[nt]) s1 = -1e30f;
                    }
                    float p0 = __expf(s0), p1 = __expf(s1);
                    lp[nt] += p0 + p1;
                    PkCast pk; pk.v = __builtin_amdgcn_cvt_pkrtz(p0, p1);
                    w[nt][p] = pk.i;
                }
            }

            // ---- C-layout -> P^T B-frags (cross-half dword exchange) ----
            f16x8 pb[2][2];
#pragma unroll
            for (int nt = 0; nt < 2; nt++)
#pragma unroll
                for (int ks = 0; ks < 2; ks++) {
                    FragCast fc;
#if __has_builtin(__builtin_amdgcn_permlane32_swap)
                    v2i r02 = __builtin_amdgcn_permlane32_swap(w[nt][4*ks+0], w[nt][4*ks+2], false, false);
                    v2i r13 = __builtin_amdgcn_permlane32_swap(w[nt][4*ks+1], w[nt][4*ks+3], false, false);
                    fc.w[0] = r02.x; fc.w[1] = r13.x; fc.w[2] = r02.y; fc.w[3] = r13.y;
#else
                    int w0 = w[nt][4*ks], w1 = w[nt][4*ks+1], w2 = w[nt][4*ks+2], w3 = w[nt][4*ks+3];
                    fc.w[0] = lh ? __shfl_xor(w2, 32) : w0;
                    fc.w[1] = lh ? __shfl_xor(w3, 32) : w1;
                    fc.w[2] = lh ? w2 : __shfl_xor(w0, 32);
                    fc.w[3] = lh ? w3 : __shfl_xor(w1, 32);
#endif
                    pb[nt][ks] = fc.v;
                }

            // ---- O^T += V^T P^T (V frags shared across both n-tiles) ----
#pragma unroll
            for (int mt = 0; mt < 4; mt++)
#pragma unroll
                for (int ks = 0; ks < 2; ks++) {
                    f16x8 va = *(const f16x8*)(smc + 16384 + voff + kt * 8192 + ks * 4096 + mt * 512);
                    oacc[mt][0] = __builtin_amdgcn_mfma_f32_32x32x16_f16(va, pb[0][ks], oacc[mt][0], 0, 0, 0);
                    oacc[mt][1] = __builtin_amdgcn_mfma_f32_32x32x16_f16(va, pb[1][ks], oacc[mt][1], 0, 0, 0);
                }
        }

        // both waves done reading buf[cur] before next iter's stage overwrites it
        __builtin_amdgcn_s_barrier();
        cur ^= 1;
    }

    // ---- l across lane-halves ----
    float lt[2], linv[2];
#pragma unroll
    for (int nt = 0; nt < 2; nt++) {
        float l = lp[nt] + __shfl_xor(lp[nt], 32);
        lt[nt] = l;
        linv[nt] = (l > 0.f) ? 1.f / l : 0.f;
    }

    // ---- epilogue through per-wave LDS (swizzled) -> coalesced global ----
    __syncthreads();
    char* ob = (char*)smem + wv * 16384;
#pragma unroll
    for (int mt = 0; mt < 4; mt++)
#pragma unroll
        for (int nt = 0; nt < 2; nt++) {
            int qloc = l31 + 32 * nt;
#pragma unroll
            for (int g4 = 0; g4 < 4; g4++) {
                f16x4 hv;
#pragma unroll
                for (int r = 0; r < 4; r++) hv[r] = (f16)(oacc[mt][nt][g4 * 4 + r] * linv[nt]);
                int c16 = g4 + 4 * mt;
                *(f16x4*)(ob + qloc * 256 + ((c16 ^ (qloc & 7)) << 4) + lh * 8) = hv;
            }
        }
    __syncthreads();

    // slot-compact partial layout: [head][slot=bx][128 q][128 d]
    size_t obase = ((size_t)(head * NSLOT + bx) * 128 + wv * 64) * HD;
#pragma unroll
    for (int a = 0; a < 4; a++)
#pragma unroll
        for (int b = 0; b < 4; b++) {
            int qloc = a * 16 + (lane >> 2);
            int c16  = (lane & 3) + 4 * b;
            f16x8 vv = *(const f16x8*)(ob + qloc * 256 + ((c16 ^ (qloc & 7)) << 4));
            *(f16x8*)(Opart + obase + (size_t)qloc * HD + c16 * 8) = vv;
        }

    if (lane < 32) {
        size_t lbase = (size_t)(head * NSLOT + bx) * 128 + wv * 64;
        lpart[lbase + l31]      = lt[0];
        lpart[lbase + l31 + 32] = lt[1];
    }
}

// ============================================================
// Combine chunk partials -> AO f16 [S][DIM]
// ============================================================
__global__ __launch_bounds__(256) void combine(const f16* __restrict__ Opart,
                                               const float* __restrict__ lpart,
                                               f16* __restrict__ AO) {
    int gid = blockIdx.x * 256 + threadIdx.x;
    if (gid >= S_LEN * NH * 16) return;
    int dc = gid & 15;
    int head = (gid >> 4) % NH;
    int q = gid / (NH * 16);
    int tt = q >> 7, qloc = q & 127;
    int base, nchunk;
    if (tt < 12)      { base = 2 * tt;             nchunk = 2; }
    else if (tt < 24) { base = 24 + 4 * (tt - 12); nchunk = 4; }
    else              { base = 72 + 6 * (tt - 24); nchunk = 6; }

    float sum[8] = {};
    float ls = 0.f;
    for (int c = 0; c < nchunk; c++) {
        size_t sbase = (size_t)(head * NSLOT + base + c) * 128 + qloc;
        float l = lpart[sbase];
        if (l > 0.f) {
            f16x8 o = *(const f16x8*)(Opart + sbase * HD + dc * 8);
#pragma unroll
            for (int j = 0; j < 8; j++) sum[j] += (float)o[j] * l;
            ls += l;
        }
    }
    float invl = 1.f / ls;
    f16x8 r;
#pragma unroll
    for (int j = 0; j < 8; j++) r[j] = (f16)(sum[j] * invl);
    *(f16x8*)(AO + (size_t)q * DIMSZ + head * HD + dc * 8) = r;
}

// ============================================================
// Output projection GEMM (m97 structure), f32 out
// ============================================================
__global__ __launch_bounds__(256) void gemm_lds(const f16* __restrict__ A,
                                                const f16* __restrict__ B,
                                                const float* __restrict__ bias,
                                                float* __restrict__ C) {
    __shared__ __align__(16) f16 Al[128 * 64];
    __shared__ __align__(16) f16 Bl[128 * 64];
    int tid = threadIdx.x;
    int lane = tid & 63, wv = tid >> 6;
    int l16 = lane & 15, quad = lane >> 4;
    int wr = (wv >> 1) * 64, wc = (wv & 1) * 64;
    int m0 = blockIdx.x * 128, n0 = blockIdx.y * 128;

    f32x4 acc[4][4] = {};

    for (int kb = 0; kb < DIMSZ; kb += 64) {
        __syncthreads();
#pragma unroll
        for (int j = 0; j < 4; j++) {
            int s = j * 256 + wv * 64 + lane;
            int r = s >> 3, cc = s & 7;
            const f16* src = A + (size_t)min(m0 + r, S_LEN - 1) * DIMSZ + kb + ((cc ^ (r & 7)) << 3);
            async16(src, (char*)Al + (j * 4096 + wv * 1024));
        }
#pragma unroll
        for (int j = 0; j < 4; j++) {
            int s = j * 256 + wv * 64 + lane;
            int r = s >> 3, cc = s & 7;
            const f16* src = B + (size_t)(n0 + r) * DIMSZ + kb + ((cc ^ (r & 7)) << 3);
            async16(src, (char*)Bl + (j * 4096 + wv * 1024));
        }
        __builtin_amdgcn_s_waitcnt(0x0f70);
        __syncthreads();

#pragma unroll
        for (int kc = 0; kc < 2; kc++) {
            f16x8 af[4], bf[4];
#pragma unroll
            for (int i = 0; i < 4; i++) {
                int ar = wr + i * 16 + l16;
                af[i] = *(const f16x8*)((const char*)Al + ar * 128 + (((kc * 4 + quad) ^ (ar & 7)) << 4));
                int br = wc + i * 16 + l16;
                bf[i] = *(const f16x8*)((const char*)Bl + br * 128 + (((kc * 4 + quad) ^ (br & 7)) << 4));
            }
#pragma unroll
            for (int mi = 0; mi < 4; mi++)
#pragma unroll
                for (int ni = 0; ni < 4; ni++)
                    acc[mi][ni] = __builtin_amdgcn_mfma_f32_16x16x32_f16(af[mi], bf[ni], acc[mi][ni], 0, 0, 0);
        }
    }

#pragma unroll
    for (int mi = 0; mi < 4; mi++)
#pragma unroll
        for (int ni = 0; ni < 4; ni++) {
            int col = n0 + wc + ni * 16 + l16;
            float bv = bias[col];
#pragma unroll
            for (int r = 0; r < 4; r++) {
                int row = m0 + wr + mi * 16 + quad * 4 + r;
                if (row < S_LEN) C[(size_t)row * DIMSZ + col] = acc[mi][ni][r] + bv;
            }
        }
}

// ============================================================
// host launch
// ============================================================
extern "C" void kernel_launch(void* const* d_in, const int* in_sizes, int n_in,
                              void* d_out, int out_size, void* d_ws, size_t ws_size,
                              hipStream_t stream) {
    const float* x     = (const float*)d_in[0];
    const float* freqs = (const float*)d_in[3];
    const float* Wq = (const float*)d_in[4];
    const float* bq = (const float*)d_in[5];
    const float* Wk = (const float*)d_in[6];
    const float* bk = (const float*)d_in[7];
    const float* Wv = (const float*)d_in[8];
    const float* bv = (const float*)d_in[9];
    const float* Wo = (const float*)d_in[10];
    const float* bo = (const float*)d_in[11];
    const float* gq = (const float*)d_in[12];
    const float* gk = (const float*)d_in[13];
    float* out = (float*)d_out;

    char* ws = (char*)d_ws;
    const size_t SZ_XH  = (size_t)S_LEN * DIMSZ * 2;     // 14,376,960
    const size_t SZ_W   = (size_t)DIMSZ * DIMSZ * 2;     //  4,718,592
    const size_t SZ_PAN = (size_t)NH * PANH * 2;         // 14,548,992
    const size_t SZ_OP  = (size_t)NH * NSLOT * 128 * HD * 2;  // 58,982,400

    size_t off = 0;
    f16* xh   = (f16*)(ws + off); off += SZ_XH;
    f16* wqh  = (f16*)(ws + off); off += 4 * SZ_W;       // wq,wk,wv,wo contiguous
    f16* wkh  = wqh + (size_t)DIMSZ * DIMSZ;
    f16* wvh  = wkh + (size_t)DIMSZ * DIMSZ;
    f16* woh  = wvh + (size_t)DIMSZ * DIMSZ;
    f16* Qpan = (f16*)(ws + off); off += SZ_PAN;
    f16* Kpan = (f16*)(ws + off); off += SZ_PAN;
    f16* Vpan = (f16*)(ws + off); off += SZ_PAN;
    f16* AO   = (f16*)(ws + off); off += SZ_XH;
    // union: {preq, prek} (f16) before attention | {Opart, lpart} after
    f16*   preq  = (f16*)(ws + off);
    f16*   prek  = preq + (size_t)S_LEN * DIMSZ;
    f16*   Opart = (f16*)(ws + off);
    float* lpart = (float*)(ws + off + SZ_OP);

    cast_all<<<dim3(7020, 5), 256, 0, stream>>>(x, Wq, Wk, Wv, Wo, xh, wqh);

    gemm_qkv<<<dim3(37, 12, 3), 256, 0, stream>>>(xh, wqh, wkh, wvh, bq, bk, bv,
                                                  preq, prek, Vpan);

    norm_rope<<<dim3(S_LEN, 2), 256, 0, stream>>>(preq, prek, gq, gk, freqs, Qpan, Kpan);

    attn_part<<<dim3(NSLOT, 12), 128, 0, stream>>>(Qpan, Kpan, Vpan, Opart, lpart);
    combine<<<(S_LEN * NH * 16 + 255) / 256, 256, 0, stream>>>(Opart, lpart, AO);

    gemm_lds<<<dim3(37, 12), 256, 0, stream>>>(AO, woh, bo, out);
}